// Round 3
// baseline (1555.465 us; speedup 1.0000x reference)
//
#include <hip/hip_runtime.h>
#include <hip/hip_bf16.h>

#define GN 16384
#define GD 128
#define KSPLIT 4
#define KBLK (GN / KSPLIT)   // 4096 k per wave
#define OUT_ELEMS (GN * GD)  // 2097152

typedef __attribute__((ext_vector_type(8))) short short8;
typedef __attribute__((ext_vector_type(4))) float floatx4;
typedef __attribute__((ext_vector_type(4))) int intx4;

static __device__ __forceinline__ unsigned short f32_to_bf16(float f) {
  unsigned u = __builtin_bit_cast(unsigned, f);
  unsigned r = u + 0x7FFFu + ((u >> 16) & 1u);  // RNE (inputs finite/normal)
  return (unsigned short)(r >> 16);
}

// Kernel 1: xT[d][j] <- bf16(x[j][d])  (4 MiB, stays L2/L3-resident for gemm)
__global__ __launch_bounds__(256) void prep_kernel(const float* __restrict__ x,
                                                   unsigned short* __restrict__ xT) {
  __shared__ unsigned short t[GD][66];  // +2 pad: 4B-aligned, conflict-free
  const int tid = threadIdx.x;
  const int j0 = blockIdx.x * 64;
  for (int i = tid; i < 64 * GD; i += 256) {
    int j = i >> 7, d = i & (GD - 1);
    t[d][j] = f32_to_bf16(x[(size_t)(j0 + j) * GD + d]);
  }
  __syncthreads();
  for (int i = tid; i < GD * 32; i += 256) {
    int d = i >> 5, jp = i & 31;
    unsigned lo = t[d][2 * jp], hi = t[d][2 * jp + 1];
    *reinterpret_cast<unsigned*>(xT + (size_t)d * GN + j0 + 2 * jp) = lo | (hi << 16);
  }
}

// Kernel 2: one wave per block; NO LDS, NO barriers. Wave owns 32 rows x all 128
// cols x 4096-k slice. adj streamed nt from HBM; B fragments read directly from
// L2-resident xT. Next k-step's 12 loads prefetched while current step's MFMAs run.
__global__ __launch_bounds__(64, 2) void gemm_kernel(const int* __restrict__ adj,
                                                     const unsigned short* __restrict__ xT,
                                                     float* __restrict__ partials) {
  const int lane = threadIdx.x;
  const int q = lane >> 4;   // 0..3
  const int m = lane & 15;   // 0..15
  const int wid = blockIdx.x;      // 0..2047
  const int rbase = (wid >> 2) * 32;
  const int ks = wid & 3;
  const int kbase = ks * KBLK;

  const int* a0 = adj + (size_t)(rbase + m) * GN + kbase + q * 8;
  const int* a1 = a0 + (size_t)16 * GN;
  const unsigned short* b0 = xT + (size_t)m * GN + kbase + q * 8;

  floatx4 acc[2][8];
#pragma unroll
  for (int t = 0; t < 2; ++t)
#pragma unroll
    for (int c = 0; c < 8; ++c) acc[t][c] = (floatx4){0.f, 0.f, 0.f, 0.f};

  // preload k = 0
  intx4 r0 = __builtin_nontemporal_load((const intx4*)(a0));
  intx4 r1 = __builtin_nontemporal_load((const intx4*)(a0 + 4));
  intx4 r2 = __builtin_nontemporal_load((const intx4*)(a1));
  intx4 r3 = __builtin_nontemporal_load((const intx4*)(a1 + 4));
  short8 bf[8];
#pragma unroll
  for (int c = 0; c < 8; ++c)
    bf[c] = *(const short8*)(b0 + (size_t)c * 16 * GN);

  for (int k = 0; k < KBLK; k += 32) {
    const int kn = (k + 32) & (KBLK - 1);  // wrap on last iter (discarded, in-bounds)

    // prefetch next step
    intx4 s0 = __builtin_nontemporal_load((const intx4*)(a0 + kn));
    intx4 s1 = __builtin_nontemporal_load((const intx4*)(a0 + kn + 4));
    intx4 s2 = __builtin_nontemporal_load((const intx4*)(a1 + kn));
    intx4 s3 = __builtin_nontemporal_load((const intx4*)(a1 + kn + 4));
    short8 nbf[8];
#pragma unroll
    for (int c = 0; c < 8; ++c)
      nbf[c] = *(const short8*)(b0 + (size_t)c * 16 * GN + kn);

    // adj int 0/1 -> bf16 0x0000/0x3F80, two elems per dword
    intx4 p0, p1;
    p0.x = (r0.x | (r0.y << 16)) * 0x3F80;
    p0.y = (r0.z | (r0.w << 16)) * 0x3F80;
    p0.z = (r1.x | (r1.y << 16)) * 0x3F80;
    p0.w = (r1.z | (r1.w << 16)) * 0x3F80;
    p1.x = (r2.x | (r2.y << 16)) * 0x3F80;
    p1.y = (r2.z | (r2.w << 16)) * 0x3F80;
    p1.z = (r3.x | (r3.y << 16)) * 0x3F80;
    p1.w = (r3.z | (r3.w << 16)) * 0x3F80;
    short8 af0 = __builtin_bit_cast(short8, p0);
    short8 af1 = __builtin_bit_cast(short8, p1);

#pragma unroll
    for (int c = 0; c < 8; ++c) {
      acc[0][c] = __builtin_amdgcn_mfma_f32_16x16x32_bf16(af0, bf[c], acc[0][c], 0, 0, 0);
      acc[1][c] = __builtin_amdgcn_mfma_f32_16x16x32_bf16(af1, bf[c], acc[1][c], 0, 0, 0);
    }

    r0 = s0; r1 = s1; r2 = s2; r3 = s3;
#pragma unroll
    for (int c = 0; c < 8; ++c) bf[c] = nbf[c];
  }

  // Epilogue: plain stores to this ksplit's partial buffer.
  // C/D layout: col=lane&15, row=q*4+reg.
  float* pp = partials + (size_t)ks * OUT_ELEMS + (size_t)rbase * GD;
#pragma unroll
  for (int t = 0; t < 2; ++t)
#pragma unroll
    for (int c = 0; c < 8; ++c)
#pragma unroll
      for (int r = 0; r < 4; ++r) {
        int row = t * 16 + q * 4 + r;
        int col = c * 16 + m;
        pp[(size_t)row * GD + col] = acc[t][c][r];
      }
}

// Kernel 3: out = x + sum of 4 partials (also un-poisons d_out)
__global__ __launch_bounds__(256) void reduce_kernel(const float* __restrict__ x,
                                                     const float* __restrict__ partials,
                                                     float* __restrict__ out) {
  size_t i = ((size_t)blockIdx.x * 256 + threadIdx.x) * 4;
  floatx4 v = *(const floatx4*)(x + i);
  v += *(const floatx4*)(partials + 0 * (size_t)OUT_ELEMS + i);
  v += *(const floatx4*)(partials + 1 * (size_t)OUT_ELEMS + i);
  v += *(const floatx4*)(partials + 2 * (size_t)OUT_ELEMS + i);
  v += *(const floatx4*)(partials + 3 * (size_t)OUT_ELEMS + i);
  *(floatx4*)(out + i) = v;
}

extern "C" void kernel_launch(void* const* d_in, const int* in_sizes, int n_in,
                              void* d_out, int out_size, void* d_ws, size_t ws_size,
                              hipStream_t stream) {
  const float* x = (const float*)d_in[0];
  const int* adj = (const int*)d_in[1];
  float* out = (float*)d_out;
  unsigned short* xT = (unsigned short*)d_ws;                      // 4 MiB
  float* partials = (float*)((char*)d_ws + (size_t)GN * GD * 2);   // 4 x 8 MiB

  prep_kernel<<<GN / 64, 256, 0, stream>>>(x, xT);
  gemm_kernel<<<(GN / 32) * KSPLIT, 64, 0, stream>>>(adj, xT, partials);
  reduce_kernel<<<OUT_ELEMS / 4 / 256, 256, 0, stream>>>(x, partials, out);
}

// Round 4
// 1372.585 us; speedup vs baseline: 1.1332x; 1.1332x over previous
//
#include <hip/hip_runtime.h>
#include <hip/hip_bf16.h>

#define GN 16384
#define GD 128
#define KSPLIT 4
#define KBLK (GN / KSPLIT)        // 4096 k per block
#define BK 64                     // k per staged period
#define NPER (KBLK / BK)          // 64 periods
#define BUF_SHORTS (GD * BK)      // 8192 shorts = 16 KB per buffer
#define OUT_ELEMS (GN * GD)

typedef __attribute__((ext_vector_type(8))) short short8;
typedef __attribute__((ext_vector_type(4))) float floatx4;
typedef __attribute__((ext_vector_type(4))) int intx4;

static __device__ __forceinline__ unsigned short f32_to_bf16(float f) {
  unsigned u = __builtin_bit_cast(unsigned, f);
  unsigned r = u + 0x7FFFu + ((u >> 16) & 1u);  // RNE (inputs finite/normal)
  return (unsigned short)(r >> 16);
}

// Kernel 1: xT[d][j] <- bf16(x[j][d])  (4 MiB, L2/L3-resident for gemm staging)
__global__ __launch_bounds__(256) void prep_kernel(const float* __restrict__ x,
                                                   unsigned short* __restrict__ xT) {
  __shared__ unsigned short t[GD][66];
  const int tid = threadIdx.x;
  const int j0 = blockIdx.x * 64;
  for (int i = tid; i < 64 * GD; i += 256) {
    int j = i >> 7, d = i & (GD - 1);
    t[d][j] = f32_to_bf16(x[(size_t)(j0 + j) * GD + d]);
  }
  __syncthreads();
  for (int i = tid; i < GD * 32; i += 256) {
    int d = i >> 5, jp = i & 31;
    unsigned lo = t[d][2 * jp], hi = t[d][2 * jp + 1];
    *reinterpret_cast<unsigned*>(xT + (size_t)d * GN + j0 + 2 * jp) = lo | (hi << 16);
  }
}

// Kernel 2: partial[ks] = adj[64 rows, kslice] @ x[kslice]
// 256 thr / 4 waves, BM=64 (16 rows/wave), BN=128 (full D), BK=64 double-buffered.
// Occupancy-first: acc = 8 floatx4 (32 VGPR), <=128 VGPR -> 4 waves/SIMD,
// 32 KB LDS -> 4 blocks/CU. Grid 1024 = 4 blocks/CU for barrier phase diversity.
// B LDS: row n (=d) holds BK k's (128 B = 8 granules); granule sg of row n stores
// source granule sg^(n&7)  ->  fragment ds_read_b128 lands 2 lanes/bank (free).
__global__ __launch_bounds__(256, 4) void gemm_kernel(const int* __restrict__ adj,
                                                      const unsigned short* __restrict__ xT,
                                                      float* __restrict__ partials) {
  __shared__ unsigned short bbuf[2][BUF_SHORTS];
  const int tid = threadIdx.x;
  const int wave = tid >> 6;
  const int lane = tid & 63;
  const int q = lane >> 4;   // 0..3
  const int m = lane & 15;   // 0..15
  const int rbase = blockIdx.x * 64 + wave * 16;
  const int ks = blockIdx.y;
  const int kbase = ks * KBLK;

  // staging: 4 granules (16 B) per thread, slot s = tid + 256p
  const unsigned short* gptr[4];
  unsigned short* lptr[4];
#pragma unroll
  for (int p = 0; p < 4; ++p) {
    int s = tid + 256 * p;          // 0..1023
    int n = s >> 3;                 // B row (= d) 0..127
    int gsrc = (s & 7) ^ (n & 7);   // XOR swizzle (involution)
    gptr[p] = xT + (size_t)n * GN + kbase + gsrc * 8;
    lptr[p] = &bbuf[0][0] + (size_t)s * 8;
  }

#define STAGE(bufsel, koff)                                                             \
  do {                                                                                  \
    _Pragma("unroll") for (int p = 0; p < 4; ++p) {                                     \
      __builtin_amdgcn_global_load_lds(                                                 \
          (const __attribute__((address_space(1))) unsigned int*)(gptr[p] + (koff)),    \
          (__attribute__((address_space(3))) unsigned int*)(lptr[p] +                   \
                                                           (bufsel) * BUF_SHORTS),      \
          16, 0, 0);                                                                    \
    }                                                                                   \
  } while (0)

  const int* a0 = adj + (size_t)(rbase + m) * GN + kbase + q * 8;

  floatx4 acc[8];
#pragma unroll
  for (int c = 0; c < 8; ++c) acc[c] = (floatx4){0.f, 0.f, 0.f, 0.f};

  STAGE(0, 0);
  intx4 ca[4];
  ca[0] = __builtin_nontemporal_load((const intx4*)(a0));
  ca[1] = __builtin_nontemporal_load((const intx4*)(a0 + 4));
  ca[2] = __builtin_nontemporal_load((const intx4*)(a0 + 32));
  ca[3] = __builtin_nontemporal_load((const intx4*)(a0 + 36));

  int buf = 0;
  for (int c = 0; c < NPER; ++c) {
    __syncthreads();  // staged buf ready; all waves done with buf^1
    const int nk = ((c + 1) & (NPER - 1)) * BK;  // wraps on last iter (discarded)
    if (c + 1 < NPER) STAGE(buf ^ 1, nk);
    intx4 na[4];
    na[0] = __builtin_nontemporal_load((const intx4*)(a0 + nk));
    na[1] = __builtin_nontemporal_load((const intx4*)(a0 + nk + 4));
    na[2] = __builtin_nontemporal_load((const intx4*)(a0 + nk + 32));
    na[3] = __builtin_nontemporal_load((const intx4*)(a0 + nk + 36));

#pragma unroll
    for (int kk = 0; kk < 2; ++kk) {
      // B frags: lane(q,m), col-tile cc -> row n=cc*16+m, in-row granule (4kk+q)^(m&7)
      short8 bf[8];
      const unsigned short* bb = &bbuf[buf][0] + ((4 * kk + q) ^ (m & 7)) * 8;
#pragma unroll
      for (int cc = 0; cc < 8; ++cc)
        bf[cc] = *(const short8*)(bb + (cc * 16 + m) * BK);

      // adj 0/1 int -> bf16 0x0000/0x3F80 (two elems per dword)
      const intx4 r0 = ca[2 * kk], r1 = ca[2 * kk + 1];
      intx4 pk;
      pk.x = (r0.x | (r0.y << 16)) * 0x3F80;
      pk.y = (r0.z | (r0.w << 16)) * 0x3F80;
      pk.z = (r1.x | (r1.y << 16)) * 0x3F80;
      pk.w = (r1.z | (r1.w << 16)) * 0x3F80;
      const short8 af = __builtin_bit_cast(short8, pk);

#pragma unroll
      for (int cc = 0; cc < 8; ++cc)
        acc[cc] = __builtin_amdgcn_mfma_f32_16x16x32_bf16(af, bf[cc], acc[cc], 0, 0, 0);
    }

#pragma unroll
    for (int u = 0; u < 4; ++u) ca[u] = na[u];
    buf ^= 1;
  }

  // Epilogue: plain stores. C/D: col=lane&15, row=q*4+reg.
  float* pp = partials + (size_t)ks * OUT_ELEMS + (size_t)rbase * GD;
#pragma unroll
  for (int cc = 0; cc < 8; ++cc)
#pragma unroll
    for (int r = 0; r < 4; ++r)
      pp[(size_t)(q * 4 + r) * GD + cc * 16 + m] = acc[cc][r];
}

// Kernel 3: out = x + sum of 4 partials (also un-poisons d_out)
__global__ __launch_bounds__(256) void reduce_kernel(const float* __restrict__ x,
                                                     const float* __restrict__ partials,
                                                     float* __restrict__ out) {
  size_t i = ((size_t)blockIdx.x * 256 + threadIdx.x) * 4;
  floatx4 v = *(const floatx4*)(x + i);
  v += *(const floatx4*)(partials + 0 * (size_t)OUT_ELEMS + i);
  v += *(const floatx4*)(partials + 1 * (size_t)OUT_ELEMS + i);
  v += *(const floatx4*)(partials + 2 * (size_t)OUT_ELEMS + i);
  v += *(const floatx4*)(partials + 3 * (size_t)OUT_ELEMS + i);
  *(floatx4*)(out + i) = v;
}

extern "C" void kernel_launch(void* const* d_in, const int* in_sizes, int n_in,
                              void* d_out, int out_size, void* d_ws, size_t ws_size,
                              hipStream_t stream) {
  const float* x = (const float*)d_in[0];
  const int* adj = (const int*)d_in[1];
  float* out = (float*)d_out;
  unsigned short* xT = (unsigned short*)d_ws;                     // 4 MiB
  float* partials = (float*)((char*)d_ws + (size_t)GN * GD * 2);  // 4 x 8 MiB

  prep_kernel<<<GN / 64, 256, 0, stream>>>(x, xT);
  gemm_kernel<<<dim3(GN / 64, KSPLIT), 256, 0, stream>>>(adj, xT, partials);
  reduce_kernel<<<OUT_ELEMS / 4 / 256, 256, 0, stream>>>(x, partials, out);
}